// Round 6
// baseline (74.280 us; speedup 1.0000x reference)
//
#include <hip/hip_runtime.h>
#include <math.h>

#define MAXR 100.0f
#define LOG2E 1.4426950408889634f
// Fixed shapes: B=4, C=64, H=64, W=64; conv (2,64,3,3) OIHW, SAME.

__device__ __forceinline__ float exp2_fast(float x) { return __builtin_amdgcn_exp2f(x); }
__device__ __forceinline__ float rcp_fast(float x)  { return __builtin_amdgcn_rcpf(x); }
__device__ __forceinline__ float bcast_lane(float v, int i) {   // i may be runtime (SGPR)
    return __int_as_float(__builtin_amdgcn_readlane(__float_as_int(v), i));
}

__device__ __forceinline__ float tanh_fast(float s) {
    // tanh(s) = sign(s) * (1 - 2/(e^{2|s|}+1)); E=inf -> t=1 exactly
    float E = exp2_fast(2.0f * LOG2E * fabsf(s));
    float t = fmaf(-2.0f, rcp_fast(E + 1.0f), 1.0f);
    return copysignf(t, s);
}

// ---- DPP wave64 reductions: VALU-only (HW-verified rounds 2-5) ----
template<int CTRL>
__device__ __forceinline__ float dpp0(float v) {
    return __int_as_float(__builtin_amdgcn_update_dpp(0, __float_as_int(v), CTRL, 0xf, 0xf, true));
}
template<int CTRL>
__device__ __forceinline__ float dppk(float v) {
    return __int_as_float(__builtin_amdgcn_update_dpp(__float_as_int(v), __float_as_int(v), CTRL, 0xf, 0xf, false));
}
__device__ __forceinline__ float wave_sum(float v) {
    v += dpp0<0x111>(v);   // row_shr:1
    v += dpp0<0x112>(v);   // row_shr:2
    v += dpp0<0x114>(v);   // row_shr:4
    v += dpp0<0x118>(v);   // row_shr:8
    v += dpp0<0x142>(v);   // row_bcast15
    v += dpp0<0x143>(v);   // row_bcast31 -> lane63 = total
    return bcast_lane(v, 63);
}
__device__ __forceinline__ float wave_max(float v) {
    v = fmaxf(v, dppk<0x111>(v));
    v = fmaxf(v, dppk<0x112>(v));
    v = fmaxf(v, dppk<0x114>(v));
    v = fmaxf(v, dppk<0x118>(v));
    v = fmaxf(v, dppk<0x142>(v));
    v = fmaxf(v, dppk<0x143>(v));
    return bcast_lane(v, 63);
}
__device__ __forceinline__ float wave_min(float v) {
    v = fminf(v, dppk<0x111>(v));
    v = fminf(v, dppk<0x112>(v));
    v = fminf(v, dppk<0x114>(v));
    v = fminf(v, dppk<0x118>(v));
    v = fminf(v, dppk<0x142>(v));
    v = fminf(v, dppk<0x143>(v));
    return bcast_lane(v, 63);
}

// 4096 blocks x 256 threads. Block = 4 consecutive-w pixels (same b,h);
// ONE pixel per wave; lane = channel.
// R6 change (isolated): conv weights staged into LDS with COALESCED global
// loads (consecutive tid -> consecutive addr, 18 lines/block), then read
// per-lane from LDS at stride 9 (gcd(9,32)=1 -> 2 lanes/bank = conflict-free).
// Replaces 18 per-lane global gathers (~36 cache lines EACH -> ~650 cy/wave
// of serialized L1/TA occupancy, the dominant fixed cost in R5's profile model).
__global__ __launch_bounds__(256) void dsf_fused(const float* __restrict__ x,
                                                 const float* __restrict__ wg,
                                                 const float* __restrict__ bias,
                                                 float* __restrict__ out) {
    __shared__ float xs[64 * 19];       // [c][r*6+wt], stride 19 (gcd(19,32)=1)
    __shared__ float wsh[1152];         // conv weights, linear copy of wg

    const int tid  = threadIdx.x;
    const int lane = tid & 63;
    const int wave = tid >> 6;

    const int p0 = blockIdx.x * 4;      // b*4096 + h*64 + w0, w0 multiple of 4
    const int b  = p0 >> 12;
    const int h  = (p0 >> 6) & 63;
    const int w0 = p0 & 63;

    // stage conv weights: perfectly coalesced (4.5 iters/thread)
    for (int e = tid; e < 1152; e += 256) wsh[e] = wg[e];

    const float b0 = bias[0], b1 = bias[1];

    // stage x[b, :, h-1:h+2, w0-1:w0+4] zero-padded into xs
    const float* xbase = x + b * 262144;
    for (int e = tid; e < 1152; e += 256) {
        int c   = e / 18;
        int rem = e - c * 18;
        int r   = rem / 6;
        int wt  = rem - r * 6;
        int hh  = h + r - 1;
        int ww  = w0 - 1 + wt;
        float v = 0.f;
        if (hh >= 0 && hh < 64 && (unsigned)ww < 64u)
            v = xbase[c * 4096 + hh * 64 + ww];
        xs[c * 19 + rem] = v;
    }
    __syncthreads();

    // per-lane weights from LDS (conflict-free 2-way)
    float wr0[9], wr1[9];
    #pragma unroll
    for (int k = 0; k < 9; ++k) {
        wr0[k] = wsh[lane * 9 + k];
        wr1[k] = wsh[576 + lane * 9 + k];
    }

    // ---- conv for this wave's pixel: lane sums its channel's 9 taps ----
    const float* xc = xs + lane * 19;
    float a0 = 0.f, a1 = 0.f;
    #pragma unroll
    for (int r = 0; r < 3; ++r) {
        #pragma unroll
        for (int t = 0; t < 3; ++t) {
            float xv = xc[r * 6 + wave + t];
            a0 = fmaf(xv, wr0[r * 3 + t], a0);
            a1 = fmaf(xv, wr1[r * 3 + t], a1);
        }
    }
    a0 = wave_sum(a0);
    a1 = wave_sum(a1);
    const float al = MAXR * tanh_fast(a0 + b0);    // alpha (wave-uniform)
    const float be = MAXR * tanh_fast(a1 + b1);    // beta
    const float aa = fabsf(al);
    const float c2 = 2.0f * LOG2E * aa;            // u = 1 - 2/(2^(c2*|d|)+1)

    const float xj = xc[6 + wave + 1];             // x[b, lane, h, w0+wave]

    // ---- pairwise stage via saturation classification (HW-verified R5) ----
    const float M  = wave_max(xj);
    const float mN = wave_min(xj);
    // thr: margin 29 (>28 needed for exact u==1.0f) absorbs mul/rcp rounding.
    const float thr = 29.0f * rcp_fast(c2);        // inf if c2==0 -> all hard
    const float bx  = be * xj;                     // this lane's value as "i"

    const bool isp = bx >= M + thr;
    const bool isn = bx <= mN - thr;
    unsigned long long pm = __ballot(isp);
    unsigned long long nm = __ballot(isn);
    unsigned long long hm = ~(pm | nm);            // hard i's (wave-uniform)

    float SP = wave_sum(isp ? bx : 0.0f);
    float SN = wave_sum(isn ? bx : 0.0f);
    int   CP = __popcll(pm);
    int   CN = __popcll(nm);

    float A = (SP - SN) + (float)(CN - CP) * xj;

    while (hm) {                                   // wave-uniform loop, ~2-4 trips
        int i = __ffsll((long long)hm) - 1;
        hm &= hm - 1;
        float s = bcast_lane(xj, i);
        float d = fabsf(fmaf(be, s, -xj));
        float m = c2 * d;
        float E = exp2_fast(m);
        float r = rcp_fast(E + 1.0f);
        A = fmaf(d, fmaf(-2.0f, r, 1.0f), A);
    }

    // logits: g_j = max(-A*|alpha|/64, -100)  (sign(alpha) cancels exactly)
    float gl = fmaxf(-A * aa * (1.0f / 64.0f), -MAXR);

    float gm = wave_max(gl);
    float ew  = exp2_fast((gl - gm) * LOG2E);
    float den = wave_sum(ew);
    float num = wave_sum(xj * ew);
    if (lane == 0) out[p0 + wave] = num * rcp_fast(den);   // den >= 1
}

extern "C" void kernel_launch(void* const* d_in, const int* in_sizes, int n_in,
                              void* d_out, int out_size, void* d_ws, size_t ws_size,
                              hipStream_t stream) {
    const float* x      = (const float*)d_in[0];   // (4,64,64,64)
    const float* conv_w = (const float*)d_in[1];   // (2,64,3,3)
    const float* conv_b = (const float*)d_in[2];   // (2,)
    float* out = (float*)d_out;                    // (4,1,64,64)
    (void)d_ws; (void)ws_size;

    dsf_fused<<<4096, 256, 0, stream>>>(x, conv_w, conv_b, out);
}